// Round 12
// baseline (156.082 us; speedup 1.0000x reference)
//
#include <hip/hip_runtime.h>
#include <hip/hip_bf16.h>

typedef short short8 __attribute__((ext_vector_type(8)));
typedef float f32x4 __attribute__((ext_vector_type(4)));
typedef float f32x16 __attribute__((ext_vector_type(16)));
typedef unsigned int u32x4 __attribute__((ext_vector_type(4)));

#define HID 4096
#define CST 68     // f32 LDS row stride for cayley kernel

#define LGKM0 do { asm volatile("s_waitcnt lgkmcnt(0)" ::: "memory"); \
                   __builtin_amdgcn_sched_barrier(0); } while (0)

__device__ __forceinline__ unsigned short f2bf(float f) {
    unsigned int u = __float_as_uint(f);
    u = (u + 0x7FFFu + ((u >> 16) & 1u)) >> 16;
    return (unsigned short)u;
}

// f32x4 = row i of SA (64x64, stride CST) times SB columns j0..j0+3
__device__ __forceinline__ f32x4 mm4(const float* SA, const float* SB, int i, int j0) {
    f32x4 acc = {0.f, 0.f, 0.f, 0.f};
#pragma unroll 8
    for (int k = 0; k < 64; ++k) {
        float a = SA[i * CST + k];
        acc += a * *reinterpret_cast<const f32x4*>(SB + k * CST + j0);
    }
    return acc;
}

// ---------- Kernel: Cayley (Neumann product form) + M-build, fused ----------
// Tables PACKED in kron 32x32x16-fragment order (verified r8/r10).
__global__ __launch_bounds__(1024) void cayley_build_kernel(
    const float* __restrict__ rul, const float* __restrict__ rvl, const float* __restrict__ dl,
    const float* __restrict__ rur, const float* __restrict__ rvr, const float* __restrict__ dr,
    const int* __restrict__ invt,
    unsigned short* __restrict__ plp, unsigned short* __restrict__ mrp)
{
    __shared__ __align__(16) float Yw[64 * CST], Aw[64 * CST], Pw[64 * CST];
    __shared__ __align__(16) float Qw[64 * CST], QTw[64 * CST];
    __shared__ float dd[64];

    const float* ru; const float* rv; const float* dv; unsigned short* ob;
    if (blockIdx.x == 0) { ru = rul; rv = rvl; dv = dl; ob = plp; }
    else                 { ru = rur; rv = rvr; dv = dr; ob = mrp; }

    const int tid = threadIdx.x;
    const int i = tid >> 4;
    const int j0 = (tid & 15) << 2;

    for (int pass = 0; pass < 2; ++pass) {
        const float* raw = (pass == 0) ? ru : rv;
#pragma unroll
        for (int q = 0; q < 4; ++q) {
            int j = j0 + q;
            float v = 0.f;
            if (j > i)      v =  raw[i * 64 + j];
            else if (j < i) v = -raw[j * 64 + i];
            Yw[i * CST + j] = 0.5f * v;
        }
        __syncthreads();
        f32x4 a = mm4(Yw, Yw, i, j0);                    // A = Y*Y
        __syncthreads();
        *reinterpret_cast<f32x4*>(Aw + i * CST + j0) = a;
        *reinterpret_cast<f32x4*>(Pw + i * CST + j0) =   // P = Y + A
            a + *reinterpret_cast<const f32x4*>(Yw + i * CST + j0);
        __syncthreads();
        a = mm4(Pw, Aw, i, j0);                          // P += P*A
        __syncthreads();
        *reinterpret_cast<f32x4*>(Pw + i * CST + j0) += a;
        __syncthreads();
        a = mm4(Aw, Aw, i, j0);                          // A = A*A
        __syncthreads();
        *reinterpret_cast<f32x4*>(Aw + i * CST + j0) = a;
        __syncthreads();
        a = mm4(Pw, Aw, i, j0);                          // P += P*A
        __syncthreads();
        f32x4 p = *reinterpret_cast<const f32x4*>(Pw + i * CST + j0) + a;
#pragma unroll
        for (int q = 0; q < 4; ++q) {
            int j = j0 + q;
            float qv = ((i == j) ? 1.f : 0.f) + 2.f * p[q];
            if (pass == 0) Qw[i * CST + j]  = qv;   // Qu[i][j]
            else           QTw[j * CST + i] = qv;   // Qv^T
        }
        __syncthreads();
    }
    if (tid < 64) { float d = dv[tid]; dd[tid] = (invt[0] != 0) ? (1.0f / d) : d; }
    __syncthreads();

    f32x4 m = {0.f, 0.f, 0.f, 0.f};
#pragma unroll 8
    for (int j = 0; j < 64; ++j) {
        float aa = Qw[i * CST + j] * dd[j];
        m += aa * *reinterpret_cast<const f32x4*>(QTw + j * CST + j0);
    }
    const int kt = i >> 4, hh = (i >> 3) & 1, e = i & 7;
#pragma unroll
    for (int q = 0; q < 4; ++q) {
        int j = j0 + q;
        unsigned short v = f2bf(m[q]);
        int dst;
        if (blockIdx.x == 0)
            dst = (((j >> 5) * 4 + kt) * 64 + (j & 31) + 32 * hh) * 8 + e;
        else
            dst = ((kt * 2 + (j >> 5)) * 64 + (j & 31) + 32 * hh) * 8 + e;
        ob[dst] = v;
    }
}

// ---------- Ablation 1: kron wave-structure, loads+stores ONLY ----------
// Exact same grid, token->wave mapping, load addresses (X+ds) and store
// addresses as the full kron; no LDS/MFMA/permlane. Value = cheap sum.
__global__ __launch_bounds__(256, 4) void abl_stream_kernel(
    const float* __restrict__ inp, const float* __restrict__ ds,
    float* __restrict__ out, int ntok)
{
    const int lane = threadIdx.x & 63;
    const int r = lane & 31;
    const int h = lane >> 5;
    const int t = blockIdx.x * 4 + (threadIdx.x >> 6);
    if (t >= ntok) return;
    const float* xt = inp + (size_t)t * HID;

    float acc = 0.f;
#pragma unroll
    for (int s = 0; s < 8; ++s) {
        const int fi = s * 512 + lane * 8;
        f32x4 x0 = *reinterpret_cast<const f32x4*>(xt + fi);
        f32x4 x1 = *reinterpret_cast<const f32x4*>(xt + fi + 4);
        f32x4 d0 = *reinterpret_cast<const f32x4*>(ds + fi);
        f32x4 d1 = *reinterpret_cast<const f32x4*>(ds + fi + 4);
#pragma unroll
        for (int e = 0; e < 4; ++e) acc += x0[e] * d0[e] + x1[e] * d1[e];
    }

    float* op = out + (size_t)t * HID;
#pragma unroll
    for (int mt2 = 0; mt2 < 2; ++mt2)
#pragma unroll
        for (int nt2 = 0; nt2 < 2; ++nt2)
#pragma unroll
            for (int g = 0; g < 16; ++g) {
                const int k = 32 * mt2 + (g & 3) + 8 * (g >> 2) + 4 * h;
                op[k * 64 + 32 * nt2 + r] = acc;
            }
}

// ---------- Ablation 2: full kron chain, NO stores (asm live-keep) ----------
__global__ __launch_bounds__(256, 4) void abl_nostore_kernel(
    const float* __restrict__ inp, const float* __restrict__ ds,
    const unsigned short* __restrict__ plp, const unsigned short* __restrict__ mrp,
    const int* __restrict__ invt, int ntok)
{
    __shared__ __align__(16) unsigned char sbuf[4][8192];
    const int w = threadIdx.x >> 6;
    const int lane = threadIdx.x & 63;
    const int r = lane & 31;
    const int h = lane >> 5;
    unsigned char* S = sbuf[w];

    const int t = blockIdx.x * 4 + w;
    if (t >= ntok) return;
    const bool inv = (invt[0] != 0);
    const float* xt = inp + (size_t)t * HID;

#pragma unroll
    for (int s = 0; s < 8; ++s) {
        const int fi = s * 512 + lane * 8;
        f32x4 x0 = *reinterpret_cast<const f32x4*>(xt + fi);
        f32x4 x1 = *reinterpret_cast<const f32x4*>(xt + fi + 4);
        f32x4 d0 = *reinterpret_cast<const f32x4*>(ds + fi);
        f32x4 d1 = *reinterpret_cast<const f32x4*>(ds + fi + 4);
        if (inv) {
#pragma unroll
            for (int e = 0; e < 4; ++e) { x0[e] /= d0[e]; x1[e] /= d1[e]; }
        } else {
            x0 *= d0; x1 *= d1;
        }
        short8 f;
#pragma unroll
        for (int e = 0; e < 4; ++e) {
            f[e]     = (short)f2bf(x0[e]);
            f[e + 4] = (short)f2bf(x1[e]);
        }
        const int m = s * 8 + (lane >> 3);
        const int c = lane & 7;
        *reinterpret_cast<short8*>(S + ((m * 8 + (c ^ (m & 7))) << 4)) = f;
    }
    LGKM0;

    unsigned int zs[4][8];
#pragma unroll
    for (int nt = 0; nt < 2; ++nt) {
        short8 b1[4];
#pragma unroll
        for (int kt = 0; kt < 4; ++kt)
            b1[kt] = *reinterpret_cast<const short8*>(
                mrp + ((kt * 2 + nt) * 64 + lane) * 8);
#pragma unroll
        for (int mt = 0; mt < 2; ++mt) {
            short8 a1[4];
#pragma unroll
            for (int kt = 0; kt < 4; ++kt)
                a1[kt] = *reinterpret_cast<const short8*>(
                    S + (((32 * mt + r) * 8 + ((2 * kt + h) ^ (r & 7))) << 4));
            f32x16 acc = {0.f};
#pragma unroll
            for (int kt = 0; kt < 4; ++kt)
                acc = __builtin_amdgcn_mfma_f32_32x32x16_bf16(a1[kt], b1[kt], acc, 0, 0, 0);
            unsigned int q[8];
#pragma unroll
            for (int p = 0; p < 8; ++p)
                q[p] = (unsigned int)f2bf(acc[2 * p]) |
                       ((unsigned int)f2bf(acc[2 * p + 1]) << 16);
            auto s02 = __builtin_amdgcn_permlane32_swap(q[0], q[2], false, false);
            auto s13 = __builtin_amdgcn_permlane32_swap(q[1], q[3], false, false);
            auto s46 = __builtin_amdgcn_permlane32_swap(q[4], q[6], false, false);
            auto s57 = __builtin_amdgcn_permlane32_swap(q[5], q[7], false, false);
            unsigned int* z = zs[mt * 2 + nt];
            z[0] = s02[0]; z[1] = s13[0]; z[2] = s02[1]; z[3] = s13[1];
            z[4] = s46[0]; z[5] = s57[0]; z[6] = s46[1]; z[7] = s57[1];
        }
    }

#pragma unroll
    for (int mt2 = 0; mt2 < 2; ++mt2) {
        short8 a2[4];
#pragma unroll
        for (int kt = 0; kt < 4; ++kt)
            a2[kt] = *reinterpret_cast<const short8*>(
                plp + ((mt2 * 4 + kt) * 64 + lane) * 8);
#pragma unroll
        for (int nt2 = 0; nt2 < 2; ++nt2) {
            f32x16 y = {0.f};
#pragma unroll
            for (int kt2 = 0; kt2 < 4; ++kt2) {
                const unsigned int* z = zs[(kt2 >> 1) * 2 + nt2];
                const int kb = (kt2 & 1) * 4;
                union { u32x4 u; short8 s; } cv;
                cv.u[0] = z[kb + 0]; cv.u[1] = z[kb + 1];
                cv.u[2] = z[kb + 2]; cv.u[3] = z[kb + 3];
                y = __builtin_amdgcn_mfma_f32_32x32x16_bf16(a2[kt2], cv.s, y, 0, 0, 0);
            }
            // live-keep every output element; no stores issued
#pragma unroll
            for (int g = 0; g < 16; ++g)
                asm volatile("" :: "v"(y[g]));
        }
    }
}

// ---------- Full kron (round-10 verified, correct output) ----------
__global__ __launch_bounds__(256, 4) void kron_kernel(
    const float* __restrict__ inp, const float* __restrict__ ds,
    const unsigned short* __restrict__ plp, const unsigned short* __restrict__ mrp,
    const int* __restrict__ invt, float* __restrict__ out, int ntok)
{
    __shared__ __align__(16) unsigned char sbuf[4][8192];
    const int w = threadIdx.x >> 6;
    const int lane = threadIdx.x & 63;
    const int r = lane & 31;
    const int h = lane >> 5;
    unsigned char* S = sbuf[w];

    const int t = blockIdx.x * 4 + w;
    if (t >= ntok) return;
    const bool inv = (invt[0] != 0);
    const float* xt = inp + (size_t)t * HID;

#pragma unroll
    for (int s = 0; s < 8; ++s) {
        const int fi = s * 512 + lane * 8;
        f32x4 x0 = *reinterpret_cast<const f32x4*>(xt + fi);
        f32x4 x1 = *reinterpret_cast<const f32x4*>(xt + fi + 4);
        f32x4 d0 = *reinterpret_cast<const f32x4*>(ds + fi);
        f32x4 d1 = *reinterpret_cast<const f32x4*>(ds + fi + 4);
        if (inv) {
#pragma unroll
            for (int e = 0; e < 4; ++e) { x0[e] /= d0[e]; x1[e] /= d1[e]; }
        } else {
            x0 *= d0; x1 *= d1;
        }
        short8 f;
#pragma unroll
        for (int e = 0; e < 4; ++e) {
            f[e]     = (short)f2bf(x0[e]);
            f[e + 4] = (short)f2bf(x1[e]);
        }
        const int m = s * 8 + (lane >> 3);
        const int c = lane & 7;
        *reinterpret_cast<short8*>(S + ((m * 8 + (c ^ (m & 7))) << 4)) = f;
    }
    LGKM0;

    unsigned int zs[4][8];
#pragma unroll
    for (int nt = 0; nt < 2; ++nt) {
        short8 b1[4];
#pragma unroll
        for (int kt = 0; kt < 4; ++kt)
            b1[kt] = *reinterpret_cast<const short8*>(
                mrp + ((kt * 2 + nt) * 64 + lane) * 8);
#pragma unroll
        for (int mt = 0; mt < 2; ++mt) {
            short8 a1[4];
#pragma unroll
            for (int kt = 0; kt < 4; ++kt)
                a1[kt] = *reinterpret_cast<const short8*>(
                    S + (((32 * mt + r) * 8 + ((2 * kt + h) ^ (r & 7))) << 4));
            f32x16 acc = {0.f};
#pragma unroll
            for (int kt = 0; kt < 4; ++kt)
                acc = __builtin_amdgcn_mfma_f32_32x32x16_bf16(a1[kt], b1[kt], acc, 0, 0, 0);
            unsigned int q[8];
#pragma unroll
            for (int p = 0; p < 8; ++p)
                q[p] = (unsigned int)f2bf(acc[2 * p]) |
                       ((unsigned int)f2bf(acc[2 * p + 1]) << 16);
            auto s02 = __builtin_amdgcn_permlane32_swap(q[0], q[2], false, false);
            auto s13 = __builtin_amdgcn_permlane32_swap(q[1], q[3], false, false);
            auto s46 = __builtin_amdgcn_permlane32_swap(q[4], q[6], false, false);
            auto s57 = __builtin_amdgcn_permlane32_swap(q[5], q[7], false, false);
            unsigned int* z = zs[mt * 2 + nt];
            z[0] = s02[0]; z[1] = s13[0]; z[2] = s02[1]; z[3] = s13[1];
            z[4] = s46[0]; z[5] = s57[0]; z[6] = s46[1]; z[7] = s57[1];
        }
    }

    float* op = out + (size_t)t * HID;
#pragma unroll
    for (int mt2 = 0; mt2 < 2; ++mt2) {
        short8 a2[4];
#pragma unroll
        for (int kt = 0; kt < 4; ++kt)
            a2[kt] = *reinterpret_cast<const short8*>(
                plp + ((mt2 * 4 + kt) * 64 + lane) * 8);
#pragma unroll
        for (int nt2 = 0; nt2 < 2; ++nt2) {
            f32x16 y = {0.f};
#pragma unroll
            for (int kt2 = 0; kt2 < 4; ++kt2) {
                const unsigned int* z = zs[(kt2 >> 1) * 2 + nt2];
                const int kb = (kt2 & 1) * 4;
                union { u32x4 u; short8 s; } cv;
                cv.u[0] = z[kb + 0]; cv.u[1] = z[kb + 1];
                cv.u[2] = z[kb + 2]; cv.u[3] = z[kb + 3];
                y = __builtin_amdgcn_mfma_f32_32x32x16_bf16(a2[kt2], cv.s, y, 0, 0, 0);
            }
#pragma unroll
            for (int g = 0; g < 16; ++g) {
                const int k = 32 * mt2 + (g & 3) + 8 * (g >> 2) + 4 * h;
                op[k * 64 + 32 * nt2 + r] = y[g];
            }
        }
    }
}

extern "C" void kernel_launch(void* const* d_in, const int* in_sizes, int n_in,
                              void* d_out, int out_size, void* d_ws, size_t ws_size,
                              hipStream_t stream) {
    const float* inp = (const float*)d_in[0];
    const float* rul = (const float*)d_in[1];
    const float* rvl = (const float*)d_in[2];
    const float* dl  = (const float*)d_in[3];
    const float* rur = (const float*)d_in[4];
    const float* rvr = (const float*)d_in[5];
    const float* dr  = (const float*)d_in[6];
    const float* ds  = (const float*)d_in[7];
    const int*   invt = (const int*)d_in[8];
    float* out = (float*)d_out;

    unsigned short* plp = (unsigned short*)d_ws;   // 4096 bf16, fragment-packed PL
    unsigned short* mrp = plp + 4096;              // 4096 bf16, fragment-packed MR

    const int ntok = in_sizes[0] / HID;
    const int nblk = (ntok + 3) / 4;

    hipLaunchKernelGGL(cayley_build_kernel, dim3(2), dim3(1024), 0, stream,
                       rul, rvl, dl, rur, rvr, dr, invt, plp, mrp);

    // --- diagnostic ablations (out overwritten by full kron afterwards) ---
    hipLaunchKernelGGL(abl_stream_kernel, dim3(nblk), dim3(256), 0, stream,
                       inp, ds, out, ntok);
    hipLaunchKernelGGL(abl_nostore_kernel, dim3(nblk), dim3(256), 0, stream,
                       inp, ds, plp, mrp, invt, ntok);

    hipLaunchKernelGGL(kron_kernel, dim3(nblk), dim3(256), 0, stream,
                       inp, ds, plp, mrp, invt, out, ntok);
}

// Round 13
// 144.979 us; speedup vs baseline: 1.0766x; 1.0766x over previous
//
#include <hip/hip_runtime.h>
#include <hip/hip_bf16.h>

typedef short short8 __attribute__((ext_vector_type(8)));
typedef float f32x4 __attribute__((ext_vector_type(4)));
typedef float f32x16 __attribute__((ext_vector_type(16)));
typedef unsigned int u32x4 __attribute__((ext_vector_type(4)));

#define HID 4096
#define CST 68     // f32 LDS row stride for cayley kernel

#define LGKM0 do { asm volatile("s_waitcnt lgkmcnt(0)" ::: "memory"); \
                   __builtin_amdgcn_sched_barrier(0); } while (0)

__device__ __forceinline__ unsigned short f2bf(float f) {
    unsigned int u = __float_as_uint(f);
    u = (u + 0x7FFFu + ((u >> 16) & 1u)) >> 16;
    return (unsigned short)u;
}

// f32x4 = row i of SA (64x64, stride CST) times SB columns j0..j0+3
__device__ __forceinline__ f32x4 mm4(const float* SA, const float* SB, int i, int j0) {
    f32x4 acc = {0.f, 0.f, 0.f, 0.f};
#pragma unroll 8
    for (int k = 0; k < 64; ++k) {
        float a = SA[i * CST + k];
        acc += a * *reinterpret_cast<const f32x4*>(SB + k * CST + j0);
    }
    return acc;
}

// ---------- Kernel: Cayley (Neumann product form) + M-build, fused ----------
// Tables PACKED in kron 32x32x16-fragment order (verified r8/r10/r11).
__global__ __launch_bounds__(1024) void cayley_build_kernel(
    const float* __restrict__ rul, const float* __restrict__ rvl, const float* __restrict__ dl,
    const float* __restrict__ rur, const float* __restrict__ rvr, const float* __restrict__ dr,
    const int* __restrict__ invt,
    unsigned short* __restrict__ plp, unsigned short* __restrict__ mrp)
{
    __shared__ __align__(16) float Yw[64 * CST], Aw[64 * CST], Pw[64 * CST];
    __shared__ __align__(16) float Qw[64 * CST], QTw[64 * CST];
    __shared__ float dd[64];

    const float* ru; const float* rv; const float* dv; unsigned short* ob;
    if (blockIdx.x == 0) { ru = rul; rv = rvl; dv = dl; ob = plp; }
    else                 { ru = rur; rv = rvr; dv = dr; ob = mrp; }

    const int tid = threadIdx.x;
    const int i = tid >> 4;
    const int j0 = (tid & 15) << 2;

    for (int pass = 0; pass < 2; ++pass) {
        const float* raw = (pass == 0) ? ru : rv;
#pragma unroll
        for (int q = 0; q < 4; ++q) {
            int j = j0 + q;
            float v = 0.f;
            if (j > i)      v =  raw[i * 64 + j];
            else if (j < i) v = -raw[j * 64 + i];
            Yw[i * CST + j] = 0.5f * v;
        }
        __syncthreads();
        f32x4 a = mm4(Yw, Yw, i, j0);                    // A = Y*Y
        __syncthreads();
        *reinterpret_cast<f32x4*>(Aw + i * CST + j0) = a;
        *reinterpret_cast<f32x4*>(Pw + i * CST + j0) =   // P = Y + A
            a + *reinterpret_cast<const f32x4*>(Yw + i * CST + j0);
        __syncthreads();
        a = mm4(Pw, Aw, i, j0);                          // P += P*A
        __syncthreads();
        *reinterpret_cast<f32x4*>(Pw + i * CST + j0) += a;
        __syncthreads();
        a = mm4(Aw, Aw, i, j0);                          // A = A*A
        __syncthreads();
        *reinterpret_cast<f32x4*>(Aw + i * CST + j0) = a;
        __syncthreads();
        a = mm4(Pw, Aw, i, j0);                          // P += P*A
        __syncthreads();
        f32x4 p = *reinterpret_cast<const f32x4*>(Pw + i * CST + j0) + a;
#pragma unroll
        for (int q = 0; q < 4; ++q) {
            int j = j0 + q;
            float qv = ((i == j) ? 1.f : 0.f) + 2.f * p[q];
            if (pass == 0) Qw[i * CST + j]  = qv;   // Qu[i][j]
            else           QTw[j * CST + i] = qv;   // Qv^T
        }
        __syncthreads();
    }
    if (tid < 64) { float d = dv[tid]; dd[tid] = (invt[0] != 0) ? (1.0f / d) : d; }
    __syncthreads();

    f32x4 m = {0.f, 0.f, 0.f, 0.f};
#pragma unroll 8
    for (int j = 0; j < 64; ++j) {
        float aa = Qw[i * CST + j] * dd[j];
        m += aa * *reinterpret_cast<const f32x4*>(QTw + j * CST + j0);
    }
    const int kt = i >> 4, hh = (i >> 3) & 1, e = i & 7;
#pragma unroll
    for (int q = 0; q < 4; ++q) {
        int j = j0 + q;
        unsigned short v = f2bf(m[q]);
        int dst;
        if (blockIdx.x == 0)
            dst = (((j >> 5) * 4 + kt) * 64 + (j & 31) + 32 * hh) * 8 + e;
        else
            dst = ((kt * 2 + (j >> 5)) * 64 + (j & 31) + 32 * hh) * 8 + e;
        ob[dst] = v;
    }
}

// ---------- Pass 1: W = bf16(X .* ds) — grid-stride, fixed-inner mapping ----------
// Thread owns a FIXED 32B slice of the token layout -> ds slice lives in regs.
// Per iter: 32B contiguous load, mul, pack, 16B contiguous store. 8 iters.
__global__ __launch_bounds__(1024) void cvt_kernel(
    const float* __restrict__ x, const float* __restrict__ dsv,
    u32x4* __restrict__ wq, const int* __restrict__ invt, int ntok)
{
    const int gt = blockIdx.x * 1024 + threadIdx.x;
    const int o  = (gt & 511) * 8;            // fixed inner f32 offset
    const int g  = gt >> 9;                   // token group
    const int ng = (gridDim.x * 1024) >> 9;   // number of groups
    const bool inv = (invt[0] != 0);

    f32x4 d0 = *reinterpret_cast<const f32x4*>(dsv + o);
    f32x4 d1 = *reinterpret_cast<const f32x4*>(dsv + o + 4);
    if (inv) {
#pragma unroll
        for (int e = 0; e < 4; ++e) { d0[e] = 1.0f / d0[e]; d1[e] = 1.0f / d1[e]; }
    }

    for (int t = g; t < ntok; t += ng) {
        const float* xt = x + (size_t)t * HID + o;
        f32x4 x0 = *reinterpret_cast<const f32x4*>(xt);
        f32x4 x1 = *reinterpret_cast<const f32x4*>(xt + 4);
        x0 *= d0; x1 *= d1;
        u32x4 pk;
        pk[0] = (unsigned int)f2bf(x0[0]) | ((unsigned int)f2bf(x0[1]) << 16);
        pk[1] = (unsigned int)f2bf(x0[2]) | ((unsigned int)f2bf(x0[3]) << 16);
        pk[2] = (unsigned int)f2bf(x1[0]) | ((unsigned int)f2bf(x1[1]) << 16);
        pk[3] = (unsigned int)f2bf(x1[2]) | ((unsigned int)f2bf(x1[3]) << 16);
        wq[((size_t)t * HID + o) >> 3] = pk;
    }
}

// ---------- Pass 2: grid-stride pipelined kron from bf16 W ----------
// 4 tokens/wave (blocked), tables persistent in regs, 2-deep A-frag prefetch:
// loads for t+2 issue BEFORE body(t)'s stores -> the wave never fully drains.
// Body (mfma1 -> f2bf pack -> permlane32_swap -> mfma2 -> direct C-layout
// stores) verbatim from the r11-verified kron2.
#define LOADA(A, T) do { \
    const unsigned short* _wt = Wb + (size_t)(T) * HID; \
    _Pragma("unroll") \
    for (int mt = 0; mt < 2; ++mt) \
    _Pragma("unroll") \
    for (int kt = 0; kt < 4; ++kt) \
        A[mt * 4 + kt] = *reinterpret_cast<const short8*>( \
            _wt + (32 * mt + r) * 64 + 16 * kt + 8 * h); \
} while (0)

#define BODY(A, T) do { \
    unsigned int zs[4][8]; \
    _Pragma("unroll") \
    for (int nt = 0; nt < 2; ++nt) { \
        _Pragma("unroll") \
        for (int mt = 0; mt < 2; ++mt) { \
            f32x16 acc = {0.f}; \
            _Pragma("unroll") \
            for (int kt = 0; kt < 4; ++kt) \
                acc = __builtin_amdgcn_mfma_f32_32x32x16_bf16( \
                    A[mt * 4 + kt], b1[kt * 2 + nt], acc, 0, 0, 0); \
            unsigned int q[8]; \
            _Pragma("unroll") \
            for (int p = 0; p < 8; ++p) \
                q[p] = (unsigned int)f2bf(acc[2 * p]) | \
                       ((unsigned int)f2bf(acc[2 * p + 1]) << 16); \
            auto s02 = __builtin_amdgcn_permlane32_swap(q[0], q[2], false, false); \
            auto s13 = __builtin_amdgcn_permlane32_swap(q[1], q[3], false, false); \
            auto s46 = __builtin_amdgcn_permlane32_swap(q[4], q[6], false, false); \
            auto s57 = __builtin_amdgcn_permlane32_swap(q[5], q[7], false, false); \
            unsigned int* z = zs[mt * 2 + nt]; \
            z[0] = s02[0]; z[1] = s13[0]; z[2] = s02[1]; z[3] = s13[1]; \
            z[4] = s46[0]; z[5] = s57[0]; z[6] = s46[1]; z[7] = s57[1]; \
        } \
    } \
    float* op = out + (size_t)(T) * HID; \
    _Pragma("unroll") \
    for (int mt2 = 0; mt2 < 2; ++mt2) { \
        _Pragma("unroll") \
        for (int nt2 = 0; nt2 < 2; ++nt2) { \
            f32x16 y = {0.f}; \
            _Pragma("unroll") \
            for (int kt2 = 0; kt2 < 4; ++kt2) { \
                const unsigned int* z = zs[(kt2 >> 1) * 2 + nt2]; \
                const int kb = (kt2 & 1) * 4; \
                union { u32x4 u; short8 s; } cv; \
                cv.u[0] = z[kb + 0]; cv.u[1] = z[kb + 1]; \
                cv.u[2] = z[kb + 2]; cv.u[3] = z[kb + 3]; \
                y = __builtin_amdgcn_mfma_f32_32x32x16_bf16( \
                    a2[mt2 * 4 + kt2], cv.s, y, 0, 0, 0); \
            } \
            _Pragma("unroll") \
            for (int g = 0; g < 16; ++g) { \
                const int k = 32 * mt2 + (g & 3) + 8 * (g >> 2) + 4 * h; \
                op[k * 64 + 32 * nt2 + r] = y[g]; \
            } \
        } \
    } \
} while (0)

__global__ __launch_bounds__(256, 2) void kron2_kernel(
    const unsigned short* __restrict__ Wb,
    const unsigned short* __restrict__ plp, const unsigned short* __restrict__ mrp,
    float* __restrict__ out, int ntok)
{
    const int lane = threadIdx.x & 63;
    const int r = lane & 31;
    const int h = lane >> 5;

    // persistent tables (64 VGPR)
    short8 b1[8], a2[8];
#pragma unroll
    for (int kt = 0; kt < 4; ++kt)
#pragma unroll
        for (int nt = 0; nt < 2; ++nt)
            b1[kt * 2 + nt] = *reinterpret_cast<const short8*>(
                mrp + ((kt * 2 + nt) * 64 + lane) * 8);
#pragma unroll
    for (int mt = 0; mt < 2; ++mt)
#pragma unroll
        for (int kt = 0; kt < 4; ++kt)
            a2[mt * 4 + kt] = *reinterpret_cast<const short8*>(
                plp + ((mt * 4 + kt) * 64 + lane) * 8);

    const int wv = blockIdx.x * 4 + (threadIdx.x >> 6);
    const int t0 = wv * 4;
    if (t0 >= ntok) return;
    const bool h1 = (t0 + 1) < ntok;
    const bool h2 = (t0 + 2) < ntok;
    const bool h3 = (t0 + 3) < ntok;

    short8 aA[8], aB[8];
    LOADA(aA, t0);
    if (h1) LOADA(aB, t0 + 1);
    BODY(aA, t0);
    if (h2) LOADA(aA, t0 + 2);
    if (h1) BODY(aB, t0 + 1);
    if (h3) LOADA(aB, t0 + 3);
    if (h2) BODY(aA, t0 + 2);
    if (h3) BODY(aB, t0 + 3);
}

// ---------- Fallback: round-10 fused kron (verified, ~84us) ----------
__global__ __launch_bounds__(256, 4) void kron_kernel(
    const float* __restrict__ inp, const float* __restrict__ ds,
    const unsigned short* __restrict__ plp, const unsigned short* __restrict__ mrp,
    const int* __restrict__ invt, float* __restrict__ out, int ntok)
{
    __shared__ __align__(16) unsigned char sbuf[4][8192];
    const int w = threadIdx.x >> 6;
    const int lane = threadIdx.x & 63;
    const int r = lane & 31;
    const int h = lane >> 5;
    unsigned char* S = sbuf[w];

    const int t = blockIdx.x * 4 + w;
    if (t >= ntok) return;
    const bool inv = (invt[0] != 0);
    const float* xt = inp + (size_t)t * HID;

#pragma unroll
    for (int s = 0; s < 8; ++s) {
        const int fi = s * 512 + lane * 8;
        f32x4 x0 = *reinterpret_cast<const f32x4*>(xt + fi);
        f32x4 x1 = *reinterpret_cast<const f32x4*>(xt + fi + 4);
        f32x4 d0 = *reinterpret_cast<const f32x4*>(ds + fi);
        f32x4 d1 = *reinterpret_cast<const f32x4*>(ds + fi + 4);
        if (inv) {
#pragma unroll
            for (int e = 0; e < 4; ++e) { x0[e] /= d0[e]; x1[e] /= d1[e]; }
        } else {
            x0 *= d0; x1 *= d1;
        }
        short8 f;
#pragma unroll
        for (int e = 0; e < 4; ++e) {
            f[e]     = (short)f2bf(x0[e]);
            f[e + 4] = (short)f2bf(x1[e]);
        }
        const int m = s * 8 + (lane >> 3);
        const int c = lane & 7;
        *reinterpret_cast<short8*>(S + ((m * 8 + (c ^ (m & 7))) << 4)) = f;
    }
    LGKM0;

    unsigned int zs[4][8];
#pragma unroll
    for (int nt = 0; nt < 2; ++nt) {
        short8 b1[4];
#pragma unroll
        for (int kt = 0; kt < 4; ++kt)
            b1[kt] = *reinterpret_cast<const short8*>(
                mrp + ((kt * 2 + nt) * 64 + lane) * 8);
#pragma unroll
        for (int mt = 0; mt < 2; ++mt) {
            short8 a1[4];
#pragma unroll
            for (int kt = 0; kt < 4; ++kt)
                a1[kt] = *reinterpret_cast<const short8*>(
                    S + (((32 * mt + r) * 8 + ((2 * kt + h) ^ (r & 7))) << 4));
            f32x16 acc = {0.f};
#pragma unroll
            for (int kt = 0; kt < 4; ++kt)
                acc = __builtin_amdgcn_mfma_f32_32x32x16_bf16(a1[kt], b1[kt], acc, 0, 0, 0);
            unsigned int q[8];
#pragma unroll
            for (int p = 0; p < 8; ++p)
                q[p] = (unsigned int)f2bf(acc[2 * p]) |
                       ((unsigned int)f2bf(acc[2 * p + 1]) << 16);
            auto s02 = __builtin_amdgcn_permlane32_swap(q[0], q[2], false, false);
            auto s13 = __builtin_amdgcn_permlane32_swap(q[1], q[3], false, false);
            auto s46 = __builtin_amdgcn_permlane32_swap(q[4], q[6], false, false);
            auto s57 = __builtin_amdgcn_permlane32_swap(q[5], q[7], false, false);
            unsigned int* z = zs[mt * 2 + nt];
            z[0] = s02[0]; z[1] = s13[0]; z[2] = s02[1]; z[3] = s13[1];
            z[4] = s46[0]; z[5] = s57[0]; z[6] = s46[1]; z[7] = s57[1];
        }
    }

    float* op = out + (size_t)t * HID;
#pragma unroll
    for (int mt2 = 0; mt2 < 2; ++mt2) {
        short8 a2[4];
#pragma unroll
        for (int kt = 0; kt < 4; ++kt)
            a2[kt] = *reinterpret_cast<const short8*>(
                plp + ((mt2 * 4 + kt) * 64 + lane) * 8);
#pragma unroll
        for (int nt2 = 0; nt2 < 2; ++nt2) {
            f32x16 y = {0.f};
#pragma unroll
            for (int kt2 = 0; kt2 < 4; ++kt2) {
                const unsigned int* z = zs[(kt2 >> 1) * 2 + nt2];
                const int kb = (kt2 & 1) * 4;
                union { u32x4 u; short8 s; } cv;
                cv.u[0] = z[kb + 0]; cv.u[1] = z[kb + 1];
                cv.u[2] = z[kb + 2]; cv.u[3] = z[kb + 3];
                y = __builtin_amdgcn_mfma_f32_32x32x16_bf16(a2[kt2], cv.s, y, 0, 0, 0);
            }
#pragma unroll
            for (int g = 0; g < 16; ++g) {
                const int k = 32 * mt2 + (g & 3) + 8 * (g >> 2) + 4 * h;
                op[k * 64 + 32 * nt2 + r] = y[g];
            }
        }
    }
}

extern "C" void kernel_launch(void* const* d_in, const int* in_sizes, int n_in,
                              void* d_out, int out_size, void* d_ws, size_t ws_size,
                              hipStream_t stream) {
    const float* inp = (const float*)d_in[0];
    const float* rul = (const float*)d_in[1];
    const float* rvl = (const float*)d_in[2];
    const float* dl  = (const float*)d_in[3];
    const float* rur = (const float*)d_in[4];
    const float* rvr = (const float*)d_in[5];
    const float* dr  = (const float*)d_in[6];
    const float* ds  = (const float*)d_in[7];
    const int*   invt = (const int*)d_in[8];
    float* out = (float*)d_out;

    unsigned short* plp = (unsigned short*)d_ws;   // 4096 bf16, fragment-packed PL
    unsigned short* mrp = plp + 4096;              // 4096 bf16, fragment-packed MR

    const int ntok = in_sizes[0] / HID;
    const size_t wbytes = (size_t)ntok * HID * 2;
    const size_t woff = 1u << 20;

    hipLaunchKernelGGL(cayley_build_kernel, dim3(2), dim3(1024), 0, stream,
                       rul, rvl, dl, rur, rvr, dr, invt, plp, mrp);

    if (ws_size >= woff + wbytes) {
        unsigned short* Wb = (unsigned short*)((char*)d_ws + woff);
        hipLaunchKernelGGL(cvt_kernel, dim3(512), dim3(1024), 0, stream,
                           inp, ds, (u32x4*)Wb, invt, ntok);
        const int nblk2 = (ntok + 15) / 16;   // 4 waves/block x 4 tokens/wave
        hipLaunchKernelGGL(kron2_kernel, dim3(nblk2), dim3(256), 0, stream,
                           Wb, plp, mrp, out, ntok);
    } else {
        const int nblk = (ntok + 3) / 4;
        hipLaunchKernelGGL(kron_kernel, dim3(nblk), dim3(256), 0, stream,
                           inp, ds, plp, mrp, invt, out, ntok);
    }
}

// Round 14
// 102.531 us; speedup vs baseline: 1.5223x; 1.4140x over previous
//
#include <hip/hip_runtime.h>
#include <hip/hip_bf16.h>

typedef short short8 __attribute__((ext_vector_type(8)));
typedef float f32x4 __attribute__((ext_vector_type(4)));
typedef float f32x16 __attribute__((ext_vector_type(16)));
typedef unsigned int u32x4 __attribute__((ext_vector_type(4)));

#define HID 4096
#define CST 68     // f32 LDS row stride for cayley kernel

#define LGKM0 do { asm volatile("s_waitcnt lgkmcnt(0)" ::: "memory"); \
                   __builtin_amdgcn_sched_barrier(0); } while (0)

__device__ __forceinline__ unsigned short f2bf(float f) {
    unsigned int u = __float_as_uint(f);
    u = (u + 0x7FFFu + ((u >> 16) & 1u)) >> 16;
    return (unsigned short)u;
}

// f32x4 = row i of SA (64x64, stride CST) times SB columns j0..j0+3
__device__ __forceinline__ f32x4 mm4(const float* SA, const float* SB, int i, int j0) {
    f32x4 acc = {0.f, 0.f, 0.f, 0.f};
#pragma unroll 8
    for (int k = 0; k < 64; ++k) {
        float a = SA[i * CST + k];
        acc += a * *reinterpret_cast<const f32x4*>(SB + k * CST + j0);
    }
    return acc;
}

// ---------- Kernel 1: Cayley (Neumann product form) + M-build, fused ----------
// grid=2 (block 0: left -> plp, block 1: right -> mrp), 1024 threads.
// BOTH tables now packed in the B-fragment role (same formula, verified for
// MR in r10's mfma1):
//   ob[(((i>>4)*2 + (j>>5))*64 + (j&31) + 32*((i>>3)&1))*8 + (i&7)] = M[i][j]
// mfma1 B (MR):  tile kt*2+nt, lane r,h, elem e -> MR[16kt+8h+e][32nt+r]
// mfma2' B (PL^T via ML): tile it*2+ct -> ML[16it+8h+e][32ct+r]
//   (B-frag of PL^T[i][c] = PL[c][i] = ML[i][c])
__global__ __launch_bounds__(1024) void cayley_build_kernel(
    const float* __restrict__ rul, const float* __restrict__ rvl, const float* __restrict__ dl,
    const float* __restrict__ rur, const float* __restrict__ rvr, const float* __restrict__ dr,
    const int* __restrict__ invt,
    unsigned short* __restrict__ plp, unsigned short* __restrict__ mrp)
{
    __shared__ __align__(16) float Yw[64 * CST], Aw[64 * CST], Pw[64 * CST];
    __shared__ __align__(16) float Qw[64 * CST], QTw[64 * CST];
    __shared__ float dd[64];

    const float* ru; const float* rv; const float* dv; unsigned short* ob;
    if (blockIdx.x == 0) { ru = rul; rv = rvl; dv = dl; ob = plp; }
    else                 { ru = rur; rv = rvr; dv = dr; ob = mrp; }

    const int tid = threadIdx.x;
    const int i = tid >> 4;
    const int j0 = (tid & 15) << 2;

    for (int pass = 0; pass < 2; ++pass) {
        const float* raw = (pass == 0) ? ru : rv;
#pragma unroll
        for (int q = 0; q < 4; ++q) {
            int j = j0 + q;
            float v = 0.f;
            if (j > i)      v =  raw[i * 64 + j];
            else if (j < i) v = -raw[j * 64 + i];
            Yw[i * CST + j] = 0.5f * v;
        }
        __syncthreads();
        f32x4 a = mm4(Yw, Yw, i, j0);                    // A = Y*Y
        __syncthreads();
        *reinterpret_cast<f32x4*>(Aw + i * CST + j0) = a;
        *reinterpret_cast<f32x4*>(Pw + i * CST + j0) =   // P = Y + A
            a + *reinterpret_cast<const f32x4*>(Yw + i * CST + j0);
        __syncthreads();
        a = mm4(Pw, Aw, i, j0);                          // P += P*A
        __syncthreads();
        *reinterpret_cast<f32x4*>(Pw + i * CST + j0) += a;
        __syncthreads();
        a = mm4(Aw, Aw, i, j0);                          // A = A*A
        __syncthreads();
        *reinterpret_cast<f32x4*>(Aw + i * CST + j0) = a;
        __syncthreads();
        a = mm4(Pw, Aw, i, j0);                          // P += P*A
        __syncthreads();
        f32x4 p = *reinterpret_cast<const f32x4*>(Pw + i * CST + j0) + a;
#pragma unroll
        for (int q = 0; q < 4; ++q) {
            int j = j0 + q;
            float qv = ((i == j) ? 1.f : 0.f) + 2.f * p[q];
            if (pass == 0) Qw[i * CST + j]  = qv;   // Qu[i][j]
            else           QTw[j * CST + i] = qv;   // Qv^T
        }
        __syncthreads();
    }
    if (tid < 64) { float d = dv[tid]; dd[tid] = (invt[0] != 0) ? (1.0f / d) : d; }
    __syncthreads();

    // M[i][j0+q] = sum_j Qu[i][j]*dd[j]*QvT[j][j0+q]
    f32x4 m = {0.f, 0.f, 0.f, 0.f};
#pragma unroll 8
    for (int j = 0; j < 64; ++j) {
        float aa = Qw[i * CST + j] * dd[j];
        m += aa * *reinterpret_cast<const f32x4*>(QTw + j * CST + j0);
    }
    const int it = i >> 4, hh = (i >> 3) & 1, e = i & 7;
#pragma unroll
    for (int q = 0; q < 4; ++q) {
        int j = j0 + q;
        ob[((it * 2 + (j >> 5)) * 64 + (j & 31) + 32 * hh) * 8 + e] = f2bf(m[q]);
    }
}

// ---------- Kernel 2: fused kron, in-register Z handoff, WIDE stores ----------
// 1 token/wave, 4 waves/block, wave-private 8KB X tile, no barriers.
// Phase A: contiguous loads -> (x*ds) -> f2bf -> swizzled LDS tile (r6-verified).
// Phase B: mfma1 Z = Xs*MR (A from LDS, B = packed table).
// Phase C: Z -> bf16 pairs, permlane32_swap (r10-verified) -> zs holds Z^T
//          rows in the A/B-fragment lane layout.
// Phase D: mfma2' Y^T = Z^T * PL^T (A = zs unchanged, B = repacked plp).
//          D-layout makes reg-quads 4 CONSECUTIVE out floats ->
//          16 f32x4 stores per token (1KB/instruction) instead of 64 scalar.
__global__ __launch_bounds__(256, 4) void kron_kernel(
    const float* __restrict__ inp, const float* __restrict__ ds,
    const unsigned short* __restrict__ plp, const unsigned short* __restrict__ mrp,
    const int* __restrict__ invt, float* __restrict__ out, int ntok)
{
    __shared__ __align__(16) unsigned char sbuf[4][8192];
    const int w = threadIdx.x >> 6;
    const int lane = threadIdx.x & 63;
    const int r = lane & 31;
    const int h = lane >> 5;
    unsigned char* S = sbuf[w];

    const int t = blockIdx.x * 4 + w;
    if (t >= ntok) return;
    const bool inv = (invt[0] != 0);
    const float* xt = inp + (size_t)t * HID;

    // ---- Phase A: stage Xs (contiguous 2KB per load pair across the wave) ----
#pragma unroll
    for (int s = 0; s < 8; ++s) {
        const int fi = s * 512 + lane * 8;
        f32x4 x0 = *reinterpret_cast<const f32x4*>(xt + fi);
        f32x4 x1 = *reinterpret_cast<const f32x4*>(xt + fi + 4);
        f32x4 d0 = *reinterpret_cast<const f32x4*>(ds + fi);
        f32x4 d1 = *reinterpret_cast<const f32x4*>(ds + fi + 4);
        if (inv) {
#pragma unroll
            for (int e = 0; e < 4; ++e) { x0[e] /= d0[e]; x1[e] /= d1[e]; }
        } else {
            x0 *= d0; x1 *= d1;
        }
        short8 f;
#pragma unroll
        for (int e = 0; e < 4; ++e) {
            f[e]     = (short)f2bf(x0[e]);
            f[e + 4] = (short)f2bf(x1[e]);
        }
        const int m = s * 8 + (lane >> 3);
        const int c = lane & 7;
        *reinterpret_cast<short8*>(S + ((m * 8 + (c ^ (m & 7))) << 4)) = f;
    }
    LGKM0;

    // ---- Phase B+C: mfma1 per tile, pack + permlane swap into zs ----
    // zs[tile = mt*2+nt][8]: post-swap packed bf16; fragment for k-tile it:
    // zs[(it>>1)*2 + lt][(it&1)*4 + 0..3]   (lane r,h holds Z^T[32lt+r][16it+8h+e])
    unsigned int zs[4][8];
#pragma unroll
    for (int nt = 0; nt < 2; ++nt) {
        short8 b1[4];
#pragma unroll
        for (int kt = 0; kt < 4; ++kt)
            b1[kt] = *reinterpret_cast<const short8*>(
                mrp + ((kt * 2 + nt) * 64 + lane) * 8);
#pragma unroll
        for (int mt = 0; mt < 2; ++mt) {
            short8 a1[4];
#pragma unroll
            for (int kt = 0; kt < 4; ++kt)
                a1[kt] = *reinterpret_cast<const short8*>(
                    S + (((32 * mt + r) * 8 + ((2 * kt + h) ^ (r & 7))) << 4));
            f32x16 acc = {0.f};
#pragma unroll
            for (int kt = 0; kt < 4; ++kt)
                acc = __builtin_amdgcn_mfma_f32_32x32x16_bf16(a1[kt], b1[kt], acc, 0, 0, 0);
            unsigned int q[8];
#pragma unroll
            for (int p = 0; p < 8; ++p)
                q[p] = (unsigned int)f2bf(acc[2 * p]) |
                       ((unsigned int)f2bf(acc[2 * p + 1]) << 16);
            auto s02 = __builtin_amdgcn_permlane32_swap(q[0], q[2], false, false);
            auto s13 = __builtin_amdgcn_permlane32_swap(q[1], q[3], false, false);
            auto s46 = __builtin_amdgcn_permlane32_swap(q[4], q[6], false, false);
            auto s57 = __builtin_amdgcn_permlane32_swap(q[5], q[7], false, false);
            unsigned int* z = zs[mt * 2 + nt];
            z[0] = s02[0]; z[1] = s13[0]; z[2] = s02[1]; z[3] = s13[1];
            z[4] = s46[0]; z[5] = s57[0]; z[6] = s46[1]; z[7] = s57[1];
        }
    }

    // ---- Phase D: mfma2' Y^T = Z^T * PL^T; f32x4 stores ----
    // D tile (lt,ct): lane r,h holds Y^T[32lt + (g&3)+8(g>>2)+4h][32ct+r]
    //   = Y[k=32ct+r][l=32lt+8q+4h+j]  -> out[k*64 + l], quads contiguous.
    float* op = out + (size_t)t * HID;
#pragma unroll
    for (int lt = 0; lt < 2; ++lt) {
#pragma unroll
        for (int ct = 0; ct < 2; ++ct) {
            f32x16 y = {0.f};
#pragma unroll
            for (int it = 0; it < 4; ++it) {
                const unsigned int* z = zs[(it >> 1) * 2 + lt];
                const int kb = (it & 1) * 4;
                union { u32x4 u; short8 s; } av;
                av.u[0] = z[kb + 0]; av.u[1] = z[kb + 1];
                av.u[2] = z[kb + 2]; av.u[3] = z[kb + 3];
                short8 bf = *reinterpret_cast<const short8*>(
                    plp + ((it * 2 + ct) * 64 + lane) * 8);
                y = __builtin_amdgcn_mfma_f32_32x32x16_bf16(av.s, bf, y, 0, 0, 0);
            }
#pragma unroll
            for (int q = 0; q < 4; ++q) {
                f32x4 v;
                v[0] = y[4 * q + 0]; v[1] = y[4 * q + 1];
                v[2] = y[4 * q + 2]; v[3] = y[4 * q + 3];
                *reinterpret_cast<f32x4*>(
                    op + (32 * ct + r) * 64 + 32 * lt + 8 * q + 4 * h) = v;
            }
        }
    }
}

extern "C" void kernel_launch(void* const* d_in, const int* in_sizes, int n_in,
                              void* d_out, int out_size, void* d_ws, size_t ws_size,
                              hipStream_t stream) {
    const float* inp = (const float*)d_in[0];
    const float* rul = (const float*)d_in[1];
    const float* rvl = (const float*)d_in[2];
    const float* dl  = (const float*)d_in[3];
    const float* rur = (const float*)d_in[4];
    const float* rvr = (const float*)d_in[5];
    const float* dr  = (const float*)d_in[6];
    const float* ds  = (const float*)d_in[7];
    const int*   invt = (const int*)d_in[8];
    float* out = (float*)d_out;

    unsigned short* plp = (unsigned short*)d_ws;   // 4096 bf16, B-role packed ML
    unsigned short* mrp = plp + 4096;              // 4096 bf16, B-role packed MR

    const int ntok = in_sizes[0] / HID;

    hipLaunchKernelGGL(cayley_build_kernel, dim3(2), dim3(1024), 0, stream,
                       rul, rvl, dl, rur, rvr, dr, invt, plp, mrp);
    const int nblk = (ntok + 3) / 4;
    hipLaunchKernelGGL(kron_kernel, dim3(nblk), dim3(256), 0, stream,
                       inp, ds, plp, mrp, invt, out, ntok);
}

// Round 15
// 82.735 us; speedup vs baseline: 1.8865x; 1.2393x over previous
//
#include <hip/hip_runtime.h>
#include <hip/hip_bf16.h>

typedef short short8 __attribute__((ext_vector_type(8)));
typedef float f32x4 __attribute__((ext_vector_type(4)));
typedef float f32x16 __attribute__((ext_vector_type(16)));
typedef unsigned int u32x4 __attribute__((ext_vector_type(4)));

#define HID 4096
#define CST 68     // f32 LDS row stride for cayley kernel
#define NG  8      // groups per block
#define TB  16     // tokens per block = 2 * NG

__device__ __forceinline__ unsigned short f2bf(float f) {
    unsigned int u = __float_as_uint(f);
    u = (u + 0x7FFFu + ((u >> 16) & 1u)) >> 16;
    return (unsigned short)u;
}

// f32x4 = row i of SA (64x64, stride CST) times SB columns j0..j0+3
__device__ __forceinline__ f32x4 mm4(const float* SA, const float* SB, int i, int j0) {
    f32x4 acc = {0.f, 0.f, 0.f, 0.f};
#pragma unroll 8
    for (int k = 0; k < 64; ++k) {
        float a = SA[i * CST + k];
        acc += a * *reinterpret_cast<const f32x4*>(SB + k * CST + j0);
    }
    return acc;
}

// ---------- Kernel 1: Cayley + M-build (r10 verbatim; verified) ----------
// plp packed for mfma2 A-role: plp[((mt*4+kt)*64+lane)*8+e]
// mrp packed for mfma1 B-role: mrp[((kt*2+nt)*64+lane)*8+e]
__global__ __launch_bounds__(1024) void cayley_build_kernel(
    const float* __restrict__ rul, const float* __restrict__ rvl, const float* __restrict__ dl,
    const float* __restrict__ rur, const float* __restrict__ rvr, const float* __restrict__ dr,
    const int* __restrict__ invt,
    unsigned short* __restrict__ plp, unsigned short* __restrict__ mrp)
{
    __shared__ __align__(16) float Yw[64 * CST], Aw[64 * CST], Pw[64 * CST];
    __shared__ __align__(16) float Qw[64 * CST], QTw[64 * CST];
    __shared__ float dd[64];

    const float* ru; const float* rv; const float* dv; unsigned short* ob;
    if (blockIdx.x == 0) { ru = rul; rv = rvl; dv = dl; ob = plp; }
    else                 { ru = rur; rv = rvr; dv = dr; ob = mrp; }

    const int tid = threadIdx.x;
    const int i = tid >> 4;
    const int j0 = (tid & 15) << 2;

    for (int pass = 0; pass < 2; ++pass) {
        const float* raw = (pass == 0) ? ru : rv;
#pragma unroll
        for (int q = 0; q < 4; ++q) {
            int j = j0 + q;
            float v = 0.f;
            if (j > i)      v =  raw[i * 64 + j];
            else if (j < i) v = -raw[j * 64 + i];
            Yw[i * CST + j] = 0.5f * v;
        }
        __syncthreads();
        f32x4 a = mm4(Yw, Yw, i, j0);
        __syncthreads();
        *reinterpret_cast<f32x4*>(Aw + i * CST + j0) = a;
        *reinterpret_cast<f32x4*>(Pw + i * CST + j0) =
            a + *reinterpret_cast<const f32x4*>(Yw + i * CST + j0);
        __syncthreads();
        a = mm4(Pw, Aw, i, j0);
        __syncthreads();
        *reinterpret_cast<f32x4*>(Pw + i * CST + j0) += a;
        __syncthreads();
        a = mm4(Aw, Aw, i, j0);
        __syncthreads();
        *reinterpret_cast<f32x4*>(Aw + i * CST + j0) = a;
        __syncthreads();
        a = mm4(Pw, Aw, i, j0);
        __syncthreads();
        f32x4 p = *reinterpret_cast<const f32x4*>(Pw + i * CST + j0) + a;
#pragma unroll
        for (int q = 0; q < 4; ++q) {
            int j = j0 + q;
            float qv = ((i == j) ? 1.f : 0.f) + 2.f * p[q];
            if (pass == 0) Qw[i * CST + j]  = qv;
            else           QTw[j * CST + i] = qv;
        }
        __syncthreads();
    }
    if (tid < 64) { float d = dv[tid]; dd[tid] = (invt[0] != 0) ? (1.0f / d) : d; }
    __syncthreads();

    f32x4 m = {0.f, 0.f, 0.f, 0.f};
#pragma unroll 8
    for (int j = 0; j < 64; ++j) {
        float aa = Qw[i * CST + j] * dd[j];
        m += aa * *reinterpret_cast<const f32x4*>(QTw + j * CST + j0);
    }
    const int kt = i >> 4, hh = (i >> 3) & 1, e = i & 7;
#pragma unroll
    for (int q = 0; q < 4; ++q) {
        int j = j0 + q;
        unsigned short v = f2bf(m[q]);
        int dst;
        if (blockIdx.x == 0)
            dst = (((j >> 5) * 4 + kt) * 64 + (j & 31) + 32 * hh) * 8 + e;
        else
            dst = ((kt * 2 + (j >> 5)) * 64 + (j & 31) + 32 * hh) * 8 + e;
        ob[dst] = v;
    }
}

// ---------- Kernel 2: producer/consumer kron ----------
// Block = 4 waves: w=0,1 CONSUMERS (one token each per group, never issue
// global loads after prologue -> their vmcnt never waited -> stores stream);
// w=2,3 PRODUCERS (only loads: linear coalesced f32x4 + swizzled ds_write).
// LDS (dynamic 80KB): xbuf[2][2][16KB f32, granule-swizzled] + dsbuf[16KB].
// Swizzle: LDS granule u holds global granule sigma(u), sigma(g)=g^((g>>4)&15)
// (involution). Sync: raw s_barrier + lgkm-only waits (consumers), vmcnt+lgkm
// (producers). Compute body = r10-verified mfma1 -> permlane -> mfma2' chain.
__global__ __launch_bounds__(256) void kron_pc_kernel(
    const float* __restrict__ inp, const float* __restrict__ dsg,
    const unsigned short* __restrict__ plp, const unsigned short* __restrict__ mrp,
    const int* __restrict__ invt, float* __restrict__ out, int ntok)
{
    extern __shared__ __align__(16) unsigned char L[];
    float* dsb = reinterpret_cast<float*>(L + 65536);

    const int w = threadIdx.x >> 6;
    const int lane = threadIdx.x & 63;
    const int r = lane & 31;
    const int h = lane >> 5;

    const int base = blockIdx.x * TB;
    if (base >= ntok) return;                   // uniform per block, pre-barrier
    const bool inv = (invt[0] != 0);

    short8 b1[8], a2[8];

    // ---------------- prologue ----------------
    if (w >= 2) {
        const int p = w - 2;
        // stage ds (16KB, split between the two producers), swizzled
#pragma unroll
        for (int it = 0; it < 8; ++it) {
            const int s = (p * 8 + it) * 64 + lane;
            const int sg = s ^ ((s >> 4) & 15);
            *reinterpret_cast<f32x4*>(dsb + sg * 4) =
                *reinterpret_cast<const f32x4*>(dsg + s * 4);
        }
        // stage group 0, token slot p
        const int t0 = base + p;
        if (t0 < ntok) {
            float* dst = reinterpret_cast<float*>(L + (0 * 2 + p) * 16384);
            const float* src = inp + (size_t)t0 * HID;
#pragma unroll
            for (int it = 0; it < 16; ++it) {
                const int s = it * 64 + lane;
                const int sg = s ^ ((s >> 4) & 15);
                *reinterpret_cast<f32x4*>(dst + sg * 4) =
                    *reinterpret_cast<const f32x4*>(src + s * 4);
            }
        }
        asm volatile("s_waitcnt vmcnt(0) lgkmcnt(0)" ::: "memory");
    } else {
        // consumers: one-time table loads (their ONLY global loads)
#pragma unroll
        for (int kt = 0; kt < 4; ++kt)
#pragma unroll
            for (int nt = 0; nt < 2; ++nt)
                b1[kt * 2 + nt] = *reinterpret_cast<const short8*>(
                    mrp + ((kt * 2 + nt) * 64 + lane) * 8);
#pragma unroll
        for (int mt = 0; mt < 2; ++mt)
#pragma unroll
            for (int kt = 0; kt < 4; ++kt)
                a2[mt * 4 + kt] = *reinterpret_cast<const short8*>(
                    plp + ((mt * 4 + kt) * 64 + lane) * 8);
    }
    __builtin_amdgcn_sched_barrier(0);
    __builtin_amdgcn_s_barrier();

    // ---------------- main loop ----------------
    for (int g = 0; g < NG; ++g) {
        if (w < 2) {
            const int t = base + g * 2 + w;
            if (t < ntok) {
                const float* xf = reinterpret_cast<const float*>(
                    L + ((g & 1) * 2 + w) * 16384);

                // build mfma1 A-fragments from swizzled LDS (X .* ds)
                short8 a1f[8];
#pragma unroll
                for (int mt = 0; mt < 2; ++mt)
#pragma unroll
                    for (int kt = 0; kt < 4; ++kt) {
                        const int R = 32 * mt + r;
                        const int c0 = 4 * kt + 2 * h;
                        const int u0 = 16 * R + (c0 ^ (R & 15));
                        const int u1 = 16 * R + ((c0 + 1) ^ (R & 15));
                        f32x4 x0 = *reinterpret_cast<const f32x4*>(xf + u0 * 4);
                        f32x4 x1 = *reinterpret_cast<const f32x4*>(xf + u1 * 4);
                        f32x4 d0 = *reinterpret_cast<const f32x4*>(dsb + u0 * 4);
                        f32x4 d1 = *reinterpret_cast<const f32x4*>(dsb + u1 * 4);
                        if (inv) {
#pragma unroll
                            for (int e = 0; e < 4; ++e) { x0[e] /= d0[e]; x1[e] /= d1[e]; }
                        } else {
                            x0 *= d0; x1 *= d1;
                        }
                        short8 f;
#pragma unroll
                        for (int e = 0; e < 4; ++e) {
                            f[e]     = (short)f2bf(x0[e]);
                            f[e + 4] = (short)f2bf(x1[e]);
                        }
                        a1f[mt * 4 + kt] = f;
                    }

                // mfma1 -> pack -> permlane swap (r10-verified)
                unsigned int zs[4][8];
#pragma unroll
                for (int nt = 0; nt < 2; ++nt)
#pragma unroll
                    for (int mt = 0; mt < 2; ++mt) {
                        f32x16 acc = {0.f};
#pragma unroll
                        for (int kt = 0; kt < 4; ++kt)
                            acc = __builtin_amdgcn_mfma_f32_32x32x16_bf16(
                                a1f[mt * 4 + kt], b1[kt * 2 + nt], acc, 0, 0, 0);
                        unsigned int q[8];
#pragma unroll
                        for (int p = 0; p < 8; ++p)
                            q[p] = (unsigned int)f2bf(acc[2 * p]) |
                                   ((unsigned int)f2bf(acc[2 * p + 1]) << 16);
                        auto s02 = __builtin_amdgcn_permlane32_swap(q[0], q[2], false, false);
                        auto s13 = __builtin_amdgcn_permlane32_swap(q[1], q[3], false, false);
                        auto s46 = __builtin_amdgcn_permlane32_swap(q[4], q[6], false, false);
                        auto s57 = __builtin_amdgcn_permlane32_swap(q[5], q[7], false, false);
                        unsigned int* z = zs[mt * 2 + nt];
                        z[0] = s02[0]; z[1] = s13[0]; z[2] = s02[1]; z[3] = s13[1];
                        z[4] = s46[0]; z[5] = s57[0]; z[6] = s46[1]; z[7] = s57[1];
                    }

                // mfma2 + scalar C-layout stores (r10-verified, clean WRITE)
                float* op = out + (size_t)t * HID;
#pragma unroll
                for (int mt2 = 0; mt2 < 2; ++mt2)
#pragma unroll
                    for (int nt2 = 0; nt2 < 2; ++nt2) {
                        f32x16 y = {0.f};
#pragma unroll
                        for (int kt2 = 0; kt2 < 4; ++kt2) {
                            const unsigned int* z = zs[(kt2 >> 1) * 2 + nt2];
                            const int kb = (kt2 & 1) * 4;
                            union { u32x4 u; short8 s; } cv;
                            cv.u[0] = z[kb + 0]; cv.u[1] = z[kb + 1];
                            cv.u[2] = z[kb + 2]; cv.u[3] = z[kb + 3];
                            y = __builtin_amdgcn_mfma_f32_32x32x16_bf16(
                                a2[mt2 * 4 + kt2], cv.s, y, 0, 0, 0);
                        }
#pragma unroll
                        for (int gg = 0; gg < 16; ++gg) {
                            const int k = 32 * mt2 + (gg & 3) + 8 * (gg >> 2) + 4 * h;
                            op[k * 64 + 32 * nt2 + r] = y[gg];
                        }
                    }
            }
            // consumer barrier prep: LDS reads retired; vmcnt (stores) untouched
            asm volatile("s_waitcnt lgkmcnt(0)" ::: "memory");
        } else {
            // producer: stage group g+1 into buffer (g+1)&1
            if (g + 1 < NG) {
                const int p = w - 2;
                const int t2 = base + (g + 1) * 2 + p;
                if (t2 < ntok) {
                    float* dst = reinterpret_cast<float*>(
                        L + (((g + 1) & 1) * 2 + p) * 16384);
                    const float* src = inp + (size_t)t2 * HID;
#pragma unroll
                    for (int it = 0; it < 16; ++it) {
                        const int s = it * 64 + lane;
                        const int sg = s ^ ((s >> 4) & 15);
                        *reinterpret_cast<f32x4*>(dst + sg * 4) =
                            *reinterpret_cast<const f32x4*>(src + s * 4);
                    }
                }
            }
            asm volatile("s_waitcnt vmcnt(0) lgkmcnt(0)" ::: "memory");
        }
        __builtin_amdgcn_sched_barrier(0);
        __builtin_amdgcn_s_barrier();
    }
}

extern "C" void kernel_launch(void* const* d_in, const int* in_sizes, int n_in,
                              void* d_out, int out_size, void* d_ws, size_t ws_size,
                              hipStream_t stream) {
    const float* inp = (const float*)d_in[0];
    const float* rul = (const float*)d_in[1];
    const float* rvl = (const float*)d_in[2];
    const float* dl  = (const float*)d_in[3];
    const float* rur = (const float*)d_in[4];
    const float* rvr = (const float*)d_in[5];
    const float* dr  = (const float*)d_in[6];
    const float* ds  = (const float*)d_in[7];
    const int*   invt = (const int*)d_in[8];
    float* out = (float*)d_out;

    unsigned short* plp = (unsigned short*)d_ws;   // 4096 bf16, A-role packed PL
    unsigned short* mrp = plp + 4096;              // 4096 bf16, B-role packed MR

    const int ntok = in_sizes[0] / HID;

    hipLaunchKernelGGL(cayley_build_kernel, dim3(2), dim3(1024), 0, stream,
                       rul, rvl, dl, rur, rvr, dr, invt, plp, mrp);
    const int nblk = (ntok + TB - 1) / TB;
    hipLaunchKernelGGL(kron_pc_kernel, dim3(nblk), dim3(256), 81920, stream,
                       inp, ds, plp, mrp, invt, out, ntok);
}